// Round 1
// baseline (9497.775 us; speedup 1.0000x reference)
//
#include <hip/hip_runtime.h>

#define BB 64
#define PP 196
#define DEc 2048
#define AA 512
#define DD 512
#define EE 512
#define VV 10000
#define TT 30
#define TM 29
#define G4 2048
#define KX 2560   // E + DE
#define KTOT 3072 // KX + DD

// workspace offsets (in floats)
#define OFF_MEAN 0
#define OFF_H    131072
#define OFF_C    163840
#define OFF_ATT1 196608
#define OFF_AWE  6619136
#define OFF_X2   6750208
#define OFF_PART 6881280
#define OFF_HH   7929856

// output offsets (in floats)
#define OUT_PRED 0
#define OUT_CAPS 18560000
#define OUT_DLEN 18561920
#define OUT_ALPH 18561984

__device__ __forceinline__ float sigm(float x){ return 1.f/(1.f+expf(-x)); }

// ---------------- mean over pixels ----------------
__global__ void k_mean(const float* __restrict__ enc, float* __restrict__ mean){
  int b = blockIdx.y;
  int d = blockIdx.x*256 + threadIdx.x;
  const float* p = enc + (size_t)(b*PP)*DEc + d;
  float s = 0.f;
  for (int i=0;i<PP;i++) s += p[(size_t)i*DEc];
  mean[b*DEc + d] = s * (1.f/196.f);
}

// ---------------- h0 = mean @ Wh + bh ; c0 = mean @ Wc + bc ----------------
__global__ void k_init(const float* __restrict__ mean,
                       const float* __restrict__ whw, const float* __restrict__ whb,
                       const float* __restrict__ wcw, const float* __restrict__ wcb,
                       float* __restrict__ h, float* __restrict__ c){
  __shared__ float me[DEc];
  int b = blockIdx.x, tid = threadIdx.x;
  for (int l=tid;l<DEc;l+=256) me[l] = mean[b*DEc+l];
  __syncthreads();
  for (int n=tid;n<DD;n+=256){
    float ha = whb[n], ca = wcb[n];
    for (int k=0;k<DEc;k++){ ha += me[k]*whw[k*DD+n]; ca += me[k]*wcw[k*DD+n]; }
    h[b*DD+n]=ha; c[b*DD+n]=ca;
  }
}

// ---------------- att1 = enc @ enc_att_w + b : [12544,2048]@[2048,512] ----------------
__global__ void k_att1(const float* __restrict__ A, const float* __restrict__ Bw,
                       const float* __restrict__ bias, float* __restrict__ C){
  __shared__ float As[64][20];
  __shared__ float Bs[16][64];
  int tid = threadIdx.x;
  int tx = tid & 15, ty = tid >> 4;
  int m0 = blockIdx.y*64, n0 = blockIdx.x*64;
  float acc[4][4] = {};
  int ar = tid >> 2, ac = (tid & 3) << 2;
  int br = tid >> 4, bc = (tid & 15) << 2;
  for (int k0=0;k0<2048;k0+=16){
    *(float4*)&As[ar][ac] = *(const float4*)&A[(size_t)(m0+ar)*2048 + k0 + ac];
    *(float4*)&Bs[br][bc] = *(const float4*)&Bw[(size_t)(k0+br)*512 + n0 + bc];
    __syncthreads();
    #pragma unroll
    for (int k=0;k<16;k++){
      float av[4], bv[4];
      #pragma unroll
      for (int i=0;i<4;i++) av[i]=As[ty*4+i][k];
      #pragma unroll
      for (int j=0;j<4;j++) bv[j]=Bs[k][tx*4+j];
      #pragma unroll
      for (int i=0;i<4;i++)
        #pragma unroll
        for (int j=0;j<4;j++) acc[i][j] += av[i]*bv[j];
    }
    __syncthreads();
  }
  #pragma unroll
  for (int i=0;i<4;i++)
    #pragma unroll
    for (int j=0;j<4;j++)
      C[(size_t)(m0+ty*4+i)*512 + n0+tx*4+j] = acc[i][j] + bias[n0+tx*4+j];
}

// ---------------- passthrough outputs ----------------
__global__ void k_misc(const int* __restrict__ caps, const int* __restrict__ clen,
                       float* __restrict__ out){
  int tid = threadIdx.x;
  for (int l=tid;l<BB*TT;l+=256) out[OUT_CAPS+l] = (float)caps[l];
  if (tid<BB) out[OUT_DLEN+tid] = (float)(clen[tid]-1);
}

// ---------------- per-step attention: att2, e, softmax, alphas, awe ----------------
__global__ void k_s1(const float* __restrict__ enc, const float* __restrict__ att1,
                     const float* __restrict__ h,
                     const float* __restrict__ daw, const float* __restrict__ dab,
                     const float* __restrict__ faw, const float* __restrict__ fab,
                     const int* __restrict__ clen,
                     float* __restrict__ awe, float* __restrict__ out, int t){
  __shared__ float h_s[DD], att2_s[AA], fw_s[AA], e_s[PP], alpha_s[PP], red[256];
  int b = blockIdx.x, tid = threadIdx.x;
  h_s[tid]      = h[b*DD+tid];
  h_s[tid+256]  = h[b*DD+tid+256];
  fw_s[tid]     = faw[tid];
  fw_s[tid+256] = faw[tid+256];
  __syncthreads();
  for (int n=tid;n<AA;n+=256){
    float a = dab[n];
    for (int k=0;k<DD;k++) a += h_s[k]*daw[k*AA+n];
    att2_s[n] = a;
  }
  __syncthreads();
  int lane = tid & 63, wid = tid >> 6;
  for (int p=wid;p<PP;p+=4){
    const float* ap = att1 + (size_t)(b*PP+p)*AA;
    float acc = 0.f;
    for (int a=lane;a<AA;a+=64){
      float v = ap[a] + att2_s[a];
      acc += fmaxf(v,0.f)*fw_s[a];
    }
    #pragma unroll
    for (int off=32;off>0;off>>=1) acc += __shfl_down(acc, off);
    if (lane==0) e_s[p] = acc + fab[0];
  }
  __syncthreads();
  float val = (tid<PP)? e_s[tid] : -3.0e38f;
  red[tid]=val; __syncthreads();
  for (int s=128;s>0;s>>=1){ if (tid<s) red[tid]=fmaxf(red[tid],red[tid+s]); __syncthreads(); }
  float m = red[0]; __syncthreads();
  float ex = (tid<PP)? expf(val-m):0.f;
  red[tid]=ex; __syncthreads();
  for (int s=128;s>0;s>>=1){ if (tid<s) red[tid]+=red[tid+s]; __syncthreads(); }
  float inv = 1.f/red[0];
  int active = (t < clen[b]-1);
  if (tid<PP){
    float al = ex*inv;
    alpha_s[tid]=al;
    out[OUT_ALPH + ((size_t)b*TM + t)*PP + tid] = active? al : 0.f;
  }
  __syncthreads();
  for (int d=tid; d<DEc; d+=256){
    float acc=0.f;
    const float* ep = enc + (size_t)(b*PP)*DEc + d;
    for (int p=0;p<PP;p++) acc += alpha_s[p]*ep[(size_t)p*DEc];
    awe[b*DEc+d]=acc;
  }
}

// ---------------- x2 = sigmoid(h @ f_beta_w + b) * awe  (all batches per block) ----------------
__global__ void k_gate(const float* __restrict__ h, const float* __restrict__ fbw,
                       const float* __restrict__ fbb, const float* __restrict__ awe,
                       float* __restrict__ x2){
  __shared__ float h_s[64][128];
  int tid = threadIdx.x;
  int dl = tid & 31, bg = tid >> 5;  // bg 0..7
  int d0 = blockIdx.x*32;
  float acc[8]={0,0,0,0,0,0,0,0};
  for (int kc=0;kc<DD;kc+=128){
    for (int l=tid;l<64*128;l+=256){ int bb=l>>7, kk=l&127; h_s[bb][kk]=h[bb*DD+kc+kk]; }
    __syncthreads();
    for (int kk=0;kk<128;kk++){
      float wv = fbw[(size_t)(kc+kk)*G4 + d0 + dl];
      #pragma unroll
      for (int j=0;j<8;j++) acc[j] += h_s[bg + j*8][kk]*wv;
    }
    __syncthreads();
  }
  float bias = fbb[d0+dl];
  #pragma unroll
  for (int j=0;j<8;j++){
    int bb = bg + j*8;
    float g = sigm(acc[j]+bias);
    x2[bb*G4 + d0+dl] = g * awe[bb*G4 + d0+dl];
  }
}

// ---------------- gates partial GEMM: [64,3072]@[3072,2048] split-K into 8 chunks ----------------
__global__ void k_s2a(const int* __restrict__ caps, const float* __restrict__ embd,
                      const float* __restrict__ x2, const float* __restrict__ h,
                      const float* __restrict__ wih, const float* __restrict__ whh,
                      float* __restrict__ part, int t){
  __shared__ float As[64][64];
  int tid = threadIdx.x;
  int nl = tid & 63, bg = tid >> 6; // 0..3
  int n0 = blockIdx.x*64;
  int k0 = blockIdx.y*384;
  float acc[16];
  #pragma unroll
  for (int j=0;j<16;j++) acc[j]=0.f;
  for (int ks=0;ks<6;ks++){
    int kb = k0 + ks*64;
    for (int l=tid;l<4096;l+=256){
      int bb=l>>6, kk=l&63;
      int k=kb+kk; float v;
      if (k<EE)       v = embd[(size_t)caps[bb*TT+t]*EE + k];
      else if (k<KX)  v = x2[bb*G4 + (k-EE)];
      else            v = h[bb*DD + (k-KX)];
      As[bb][kk]=v;
    }
    __syncthreads();
    for (int kk=0;kk<64;kk++){
      int k = kb+kk;
      float wv = (k<KX)? wih[(size_t)k*G4 + n0+nl] : whh[(size_t)(k-KX)*G4 + n0+nl];
      #pragma unroll
      for (int j=0;j<16;j++) acc[j] += As[bg + j*4][kk]*wv;
    }
    __syncthreads();
  }
  #pragma unroll
  for (int j=0;j<16;j++){
    int bb = bg + j*4;
    part[(size_t)blockIdx.y*(BB*G4) + bb*G4 + n0+nl] = acc[j];
  }
}

// ---------------- LSTM cell elementwise + partial reduction ----------------
__global__ void k_s2b(const float* __restrict__ part, const float* __restrict__ bih,
                      const float* __restrict__ bhh, const int* __restrict__ clen,
                      float* __restrict__ h, float* __restrict__ c,
                      float* __restrict__ hh, int t){
  int idx = blockIdx.x*256 + threadIdx.x; // 0..32767
  int b = idx >> 9, d = idx & 511;
  float gi = bih[d]      + bhh[d];
  float gf = bih[512+d]  + bhh[512+d];
  float gg = bih[1024+d] + bhh[1024+d];
  float go = bih[1536+d] + bhh[1536+d];
  for (int ch=0;ch<8;ch++){
    const float* p = part + (size_t)ch*(BB*G4) + b*G4;
    gi += p[d]; gf += p[512+d]; gg += p[1024+d]; go += p[1536+d];
  }
  float cn = sigm(gf)*c[idx] + sigm(gi)*tanhf(gg);
  float hn = sigm(go)*tanhf(cn);
  hh[(size_t)(t*BB + b)*DD + d] = hn;
  if (t < clen[b]-1){ h[idx]=hn; c[idx]=cn; }
}

// ---------------- batched preds GEMM: [1856,512]@[512,10000], masked write ----------------
__global__ void k_preds(const float* __restrict__ Hh, const float* __restrict__ W,
                        const float* __restrict__ bias, const int* __restrict__ clen,
                        float* __restrict__ out){
  __shared__ float As[64][20];
  __shared__ float Bs[16][64];
  int tid=threadIdx.x, tx=tid&15, ty=tid>>4;
  int m0=blockIdx.y*64, n0=blockIdx.x*64;
  float acc[4][4]={};
  int ar=tid>>2, ac=(tid&3)<<2;
  int br=tid>>4, bc=(tid&15)<<2;
  for (int k0=0;k0<512;k0+=16){
    *(float4*)&As[ar][ac] = *(const float4*)&Hh[(size_t)(m0+ar)*512 + k0+ac];
    #pragma unroll
    for (int j=0;j<4;j++){
      int col = n0+bc+j;
      Bs[br][bc+j] = (col<VV)? W[(size_t)(k0+br)*VV + col] : 0.f;
    }
    __syncthreads();
    #pragma unroll
    for (int k=0;k<16;k++){
      float av[4], bv[4];
      #pragma unroll
      for (int i=0;i<4;i++) av[i]=As[ty*4+i][k];
      #pragma unroll
      for (int j=0;j<4;j++) bv[j]=Bs[k][tx*4+j];
      #pragma unroll
      for (int i=0;i<4;i++)
        #pragma unroll
        for (int j=0;j<4;j++) acc[i][j] += av[i]*bv[j];
    }
    __syncthreads();
  }
  #pragma unroll
  for (int i=0;i<4;i++){
    int r = m0+ty*4+i; int tt = r>>6, bb = r&63;
    int active = tt < clen[bb]-1;
    #pragma unroll
    for (int j=0;j<4;j++){
      int col = n0+tx*4+j;
      if (col<VV){
        float v = acc[i][j] + bias[col];
        out[OUT_PRED + ((size_t)bb*TM + tt)*VV + col] = active? v : 0.f;
      }
    }
  }
}

extern "C" void kernel_launch(void* const* d_in, const int* in_sizes, int n_in,
                              void* d_out, int out_size, void* d_ws, size_t ws_size,
                              hipStream_t stream){
  (void)in_sizes; (void)n_in; (void)out_size; (void)ws_size;
  const float* enc = (const float*)d_in[0];
  const int*   caps= (const int*)d_in[1];
  const int*   clen= (const int*)d_in[2];
  const float* embd= (const float*)d_in[3];
  const float* eaw = (const float*)d_in[4];
  const float* eab = (const float*)d_in[5];
  const float* daw = (const float*)d_in[6];
  const float* dab = (const float*)d_in[7];
  const float* faw = (const float*)d_in[8];
  const float* fab = (const float*)d_in[9];
  const float* ihw = (const float*)d_in[10];
  const float* ihb = (const float*)d_in[11];
  const float* icw = (const float*)d_in[12];
  const float* icb = (const float*)d_in[13];
  const float* fbw = (const float*)d_in[14];
  const float* fbb = (const float*)d_in[15];
  const float* wih = (const float*)d_in[16];
  const float* whh = (const float*)d_in[17];
  const float* bih = (const float*)d_in[18];
  const float* bhh = (const float*)d_in[19];
  const float* fcw = (const float*)d_in[20];
  const float* fcb = (const float*)d_in[21];

  float* ws   = (float*)d_ws;
  float* out  = (float*)d_out;
  float* mean = ws+OFF_MEAN;
  float* h    = ws+OFF_H;
  float* c    = ws+OFF_C;
  float* att1 = ws+OFF_ATT1;
  float* awe  = ws+OFF_AWE;
  float* x2   = ws+OFF_X2;
  float* part = ws+OFF_PART;
  float* hh   = ws+OFF_HH;

  k_mean<<<dim3(8,64),256,0,stream>>>(enc, mean);
  k_init<<<64,256,0,stream>>>(mean, ihw, ihb, icw, icb, h, c);
  k_att1<<<dim3(8,196),256,0,stream>>>(enc, eaw, eab, att1);
  k_misc<<<1,256,0,stream>>>(caps, clen, out);

  for (int t=0;t<TM;t++){
    k_s1 <<<64,256,0,stream>>>(enc, att1, h, daw, dab, faw, fab, clen, awe, out, t);
    k_gate<<<64,256,0,stream>>>(h, fbw, fbb, awe, x2);
    k_s2a<<<dim3(32,8),256,0,stream>>>(caps, embd, x2, h, wih, whh, part, t);
    k_s2b<<<128,256,0,stream>>>(part, bih, bhh, clen, h, c, hh, t);
  }

  k_preds<<<dim3(157,29),256,0,stream>>>(hh, fcw, fcb, clen, out);
}

// Round 2
// 2923.080 us; speedup vs baseline: 3.2492x; 3.2492x over previous
//
#include <hip/hip_runtime.h>

typedef short v8s __attribute__((ext_vector_type(8)));
typedef float v4f __attribute__((ext_vector_type(4)));

// ---- workspace offsets (bytes) ----
#define O_ENCH  0ul            // enc_hi bf16 [12544][2048]            51,380,224
#define O_ATT1  51380224ul     // att1 f32   [12544][512]              25,690,112
#define O_PEH   77070336ul     // packed eaw hi  (KT=64, NT=32)         2,097,152
#define O_PEL   79167488ul     // packed eaw lo                         2,097,152
#define O_PSM   81264640ul     // packed [daw|fbw] (KT=16, NT=160)      2,621,440
#define O_PGH   83886080ul     // packed [wih;whh] hi (KT=96, NT=128)  12,582,912
#define O_PGL   96468992ul     // packed [wih;whh] lo                  12,582,912
#define O_PFC   109051904ul    // packed fcw (KT=16, NT=640, pad)      10,485,760
#define O_PIN   119537664ul    // packed [ihw|icw] (KT=64, NT=64)       4,194,304
#define O_MEAN  123731968ul    // mean f32 [64][2048]                     524,288
#define O_MEANB 124256256ul    // mean bf16                               262,144
#define O_H     124518400ul    // h f32 [64][512]                         131,072
#define O_C     124649472ul    // c f32                                   131,072
#define O_AT2   124780544ul    // att2 f32 [64][512]                      131,072
#define O_GATE  124911616ul    // gate f32 [64][2048]                     524,288
#define O_XHI   125435904ul    // x bf16 [64][3072] = [emb|x2|h]          393,216
#define O_PART  125829120ul    // gates partials f32 [4][64][2048]      2,097,152
#define O_HHB   127926272ul    // hh bf16 [1856][512]                   1,900,544

// ---- output offsets (floats) ----
#define OUT_PRED 0ul
#define OUT_CAPS 18560000ul
#define OUT_DLEN 18561920ul
#define OUT_ALPH 18561984ul

__device__ __forceinline__ float sigm(float x){ return 1.f/(1.f+expf(-x)); }
__device__ __forceinline__ unsigned short f2bf(float f){
  union{float f; unsigned u;} v; v.f=f;
  unsigned r = v.u + 0x7FFF + ((v.u>>16)&1);
  return (unsigned short)(r>>16);
}
__device__ __forceinline__ float bf2f(unsigned short u){
  union{unsigned u; float f;} v; v.u = ((unsigned)u)<<16; return v.f;
}

// ---------------- enc fp32 -> bf16 ----------------
__global__ void k_cvt_enc(const float* __restrict__ src, unsigned short* __restrict__ dst){
  size_t base = ((size_t)blockIdx.x*256 + threadIdx.x)*8;
  float4 v0 = *(const float4*)(src+base), v1 = *(const float4*)(src+base+4);
  union { v8s v; unsigned short s[8]; } U;
  U.s[0]=f2bf(v0.x); U.s[1]=f2bf(v0.y); U.s[2]=f2bf(v0.z); U.s[3]=f2bf(v0.w);
  U.s[4]=f2bf(v1.x); U.s[5]=f2bf(v1.y); U.s[6]=f2bf(v1.z); U.s[7]=f2bf(v1.w);
  *(v8s*)(dst+base) = U.v;
}

// ---------------- mean over pixels (+bf16 copy) ----------------
__global__ void k_mean(const float* __restrict__ enc, float* __restrict__ mean,
                       unsigned short* __restrict__ meanb){
  int b = blockIdx.y;
  int d = blockIdx.x*256 + threadIdx.x;
  const float* p = enc + (size_t)(b*196)*2048 + d;
  float s = 0.f;
  for (int i=0;i<196;i++) s += p[(size_t)i*2048];
  s *= (1.f/196.f);
  mean[b*2048 + d] = s;
  meanb[b*2048 + d] = f2bf(s);
}

// ---------------- weight packing to MFMA B-fragment order ----------------
// pb[((nt*KT+kt)*64+l)*8+i] = B[kt*32+8*(l>>4)+i][nt*16+(l&15)]
__global__ void pack_eaw(const float* __restrict__ src, unsigned short* __restrict__ dh,
                         unsigned short* __restrict__ dl){
  int id = blockIdx.x*256 + threadIdx.x;            // 131072
  int l = id & 63, kt = (id>>6) & 63, nt = id >> 12;
  int k = kt*32 + (l>>4)*8, n = nt*16 + (l&15);
  union { v8s v; unsigned short s[8]; } H, L;
  #pragma unroll
  for (int i=0;i<8;i++){
    float v = src[(size_t)(k+i)*512 + n];
    unsigned short hb = f2bf(v);
    H.s[i] = hb; L.s[i] = f2bf(v - bf2f(hb));
  }
  *(v8s*)(dh + (size_t)id*8) = H.v;
  *(v8s*)(dl + (size_t)id*8) = L.v;
}
__global__ void pack_small(const float* __restrict__ daw, const float* __restrict__ fbw,
                           unsigned short* __restrict__ d){
  int id = blockIdx.x*256 + threadIdx.x;            // 163840
  int l = id & 63, kt = (id>>6) & 15, nt = id >> 10;
  int k = kt*32 + (l>>4)*8, n = nt*16 + (l&15);
  union { v8s v; unsigned short s[8]; } U;
  #pragma unroll
  for (int i=0;i<8;i++){
    float v = (n < 512) ? daw[(size_t)(k+i)*512 + n] : fbw[(size_t)(k+i)*2048 + (n-512)];
    U.s[i] = f2bf(v);
  }
  *(v8s*)(d + (size_t)id*8) = U.v;
}
__global__ void pack_gates(const float* __restrict__ wih, const float* __restrict__ whh,
                           unsigned short* __restrict__ dh, unsigned short* __restrict__ dl){
  int id = blockIdx.x*256 + threadIdx.x;            // 786432
  int l = id & 63, tmp = id>>6, kt = tmp % 96, nt = tmp / 96;
  int k0 = kt*32 + (l>>4)*8, n = nt*16 + (l&15);
  union { v8s v; unsigned short s[8]; } H, L;
  #pragma unroll
  for (int i=0;i<8;i++){
    int k = k0 + i;
    float v = (k < 2560) ? wih[(size_t)k*2048 + n] : whh[(size_t)(k-2560)*2048 + n];
    unsigned short hb = f2bf(v);
    H.s[i] = hb; L.s[i] = f2bf(v - bf2f(hb));
  }
  *(v8s*)(dh + (size_t)id*8) = H.v;
  *(v8s*)(dl + (size_t)id*8) = L.v;
}
__global__ void pack_fc(const float* __restrict__ src, unsigned short* __restrict__ d){
  int id = blockIdx.x*256 + threadIdx.x;            // 655360
  int l = id & 63, kt = (id>>6) & 15, nt = id >> 10;
  int k = kt*32 + (l>>4)*8, n = nt*16 + (l&15);
  union { v8s v; unsigned short s[8]; } U;
  #pragma unroll
  for (int i=0;i<8;i++){
    float v = (n < 10000) ? src[(size_t)(k+i)*10000 + n] : 0.f;
    U.s[i] = f2bf(v);
  }
  *(v8s*)(d + (size_t)id*8) = U.v;
}
__global__ void pack_init(const float* __restrict__ ihw, const float* __restrict__ icw,
                          unsigned short* __restrict__ d){
  int id = blockIdx.x*256 + threadIdx.x;            // 262144
  int l = id & 63, kt = (id>>6) & 63, nt = id >> 12;
  int k = kt*32 + (l>>4)*8, n = nt*16 + (l&15);
  union { v8s v; unsigned short s[8]; } U;
  #pragma unroll
  for (int i=0;i<8;i++){
    float v = (n < 512) ? ihw[(size_t)(k+i)*512 + n] : icw[(size_t)(k+i)*512 + (n-512)];
    U.s[i] = f2bf(v);
  }
  *(v8s*)(d + (size_t)id*8) = U.v;
}

// ---------------- att1 = enc @ eaw + eab : dual-B MFMA, fp32 out ----------------
__global__ __launch_bounds__(256) void g_att1(const unsigned short* __restrict__ A,
    const unsigned short* __restrict__ BH, const unsigned short* __restrict__ BL,
    const float* __restrict__ bias, float* __restrict__ C){
  int log = ((blockIdx.x & 7) * 49) + (blockIdx.x >> 3);   // 392 blocks, XCD swizzle
  int mb = log % 196, nb = log / 196;
  int tid = threadIdx.x, w = tid >> 6, l = tid & 63;
  int r = l & 15, g = l >> 4;
  int m0 = mb * 64;
  int n0 = nb * 256 + w * 64;
  int nt0 = n0 >> 4;
  const unsigned short* a0 = A + (size_t)(m0 + r) * 2048 + g * 8;
  v4f acc[4][4];
  #pragma unroll
  for (int i=0;i<4;i++){ acc[i][0]=0.f; acc[i][1]=0.f; acc[i][2]=0.f; acc[i][3]=0.f; }
  for (int kt = 0; kt < 64; ++kt){
    v8s a[4];
    #pragma unroll
    for (int mi=0;mi<4;mi++)
      a[mi] = *(const v8s*)(a0 + (size_t)mi*16*2048 + kt*32);
    #pragma unroll
    for (int nj=0;nj<4;nj++){
      size_t bi = (((size_t)(nt0+nj)*64 + kt)*64 + l)*8;
      v8s bh = *(const v8s*)(BH + bi);
      v8s bl = *(const v8s*)(BL + bi);
      #pragma unroll
      for (int mi=0;mi<4;mi++){
        acc[mi][nj] = __builtin_amdgcn_mfma_f32_16x16x32_bf16(a[mi], bh, acc[mi][nj],0,0,0);
        acc[mi][nj] = __builtin_amdgcn_mfma_f32_16x16x32_bf16(a[mi], bl, acc[mi][nj],0,0,0);
      }
    }
  }
  #pragma unroll
  for (int nj=0;nj<4;nj++){
    int col = n0 + nj*16 + r;
    float bv = bias[col];
    #pragma unroll
    for (int mi=0;mi<4;mi++){
      int row = m0 + mi*16 + g*4;
      #pragma unroll
      for (int rr=0;rr<4;rr++)
        C[(size_t)(row+rr)*512 + col] = acc[mi][nj][rr] + bv;
    }
  }
}

// ---------------- h0/c0 init MFMA: mean_bf @ [ihw|icw] ----------------
__global__ __launch_bounds__(256) void g_init(const unsigned short* __restrict__ A,
    const unsigned short* __restrict__ B, const float* __restrict__ ihb,
    const float* __restrict__ icb, float* __restrict__ h, float* __restrict__ c,
    unsigned short* __restrict__ xhi){
  int nb = blockIdx.x;                               // 16
  int tid = threadIdx.x, w = tid >> 6, l = tid & 63;
  int r = l & 15, g = l >> 4;
  int n0 = nb*64, nt0 = n0 >> 4;
  const unsigned short* a0 = A + (size_t)(w*16 + r)*2048 + g*8;
  v4f acc[4];
  #pragma unroll
  for (int j=0;j<4;j++) acc[j] = 0.f;
  for (int kt=0; kt<64; ++kt){
    v8s a = *(const v8s*)(a0 + kt*32);
    #pragma unroll
    for (int nj=0;nj<4;nj++){
      v8s b = *(const v8s*)(B + (((size_t)(nt0+nj)*64 + kt)*64 + l)*8);
      acc[nj] = __builtin_amdgcn_mfma_f32_16x16x32_bf16(a, b, acc[nj],0,0,0);
    }
  }
  #pragma unroll
  for (int nj=0;nj<4;nj++){
    int col = n0 + nj*16 + r;
    #pragma unroll
    for (int rr=0;rr<4;rr++){
      int b_ = w*16 + g*4 + rr;
      float v = acc[nj][rr];
      if (col < 512){
        float hv = v + ihb[col];
        h[b_*512 + col] = hv;
        xhi[(size_t)b_*3072 + 2560 + col] = f2bf(hv);
      } else {
        c[b_*512 + (col-512)] = v + icb[col-512];
      }
    }
  }
}

// ---------------- fused att2 + f_beta gate MFMA: h_bf @ [daw|fbw] ----------------
__global__ __launch_bounds__(256) void g_small(const unsigned short* __restrict__ X,
    const unsigned short* __restrict__ B, const float* __restrict__ dab,
    const float* __restrict__ fbb, float* __restrict__ at2, float* __restrict__ gate){
  int nb = blockIdx.x;                               // 40
  int tid = threadIdx.x, w = tid >> 6, l = tid & 63;
  int r = l & 15, g = l >> 4;
  int n0 = nb*64, nt0 = n0 >> 4;
  const unsigned short* a0 = X + (size_t)(w*16 + r)*3072 + 2560 + g*8;
  v4f acc[4];
  #pragma unroll
  for (int j=0;j<4;j++) acc[j] = 0.f;
  for (int kt=0; kt<16; ++kt){
    v8s a = *(const v8s*)(a0 + kt*32);
    #pragma unroll
    for (int nj=0;nj<4;nj++){
      v8s b = *(const v8s*)(B + (((size_t)(nt0+nj)*16 + kt)*64 + l)*8);
      acc[nj] = __builtin_amdgcn_mfma_f32_16x16x32_bf16(a, b, acc[nj],0,0,0);
    }
  }
  #pragma unroll
  for (int nj=0;nj<4;nj++){
    int col = n0 + nj*16 + r;
    #pragma unroll
    for (int rr=0;rr<4;rr++){
      int b_ = w*16 + g*4 + rr;
      float v = acc[nj][rr];
      if (col < 512) at2[b_*512 + col] = v + dab[col];
      else           gate[b_*2048 + (col-512)] = sigm(v + fbb[col-512]);
    }
  }
}

// ---------------- fused e + softmax + awe + gate*awe -> x_hi ----------------
__global__ __launch_bounds__(256) void k_attn(const float* __restrict__ att1,
    const float* __restrict__ at2, const float* __restrict__ faw,
    const float* __restrict__ fab, const unsigned short* __restrict__ ench,
    const float* __restrict__ gate, const int* __restrict__ clen,
    unsigned short* __restrict__ xhi, float* __restrict__ out, int t){
  __shared__ float es[200], red[256];
  int b = blockIdx.x >> 2, q = blockIdx.x & 3;
  int tid = threadIdx.x, w = tid >> 6, l = tid & 63;
  float a2r[8], fwr[8];
  #pragma unroll
  for (int j=0;j<8;j++){ a2r[j] = at2[b*512 + l*8 + j]; fwr[j] = faw[l*8+j]; }
  float fb = fab[0];
  for (int p = w; p < 196; p += 4){
    const float* ap = att1 + (size_t)(b*196 + p)*512 + l*8;
    float4 v0 = *(const float4*)ap;
    float4 v1 = *(const float4*)(ap+4);
    float s;
    s  = fmaxf(v0.x + a2r[0], 0.f)*fwr[0];
    s += fmaxf(v0.y + a2r[1], 0.f)*fwr[1];
    s += fmaxf(v0.z + a2r[2], 0.f)*fwr[2];
    s += fmaxf(v0.w + a2r[3], 0.f)*fwr[3];
    s += fmaxf(v1.x + a2r[4], 0.f)*fwr[4];
    s += fmaxf(v1.y + a2r[5], 0.f)*fwr[5];
    s += fmaxf(v1.z + a2r[6], 0.f)*fwr[6];
    s += fmaxf(v1.w + a2r[7], 0.f)*fwr[7];
    #pragma unroll
    for (int off=32; off>0; off>>=1) s += __shfl_down(s, off);
    if (l == 0) es[p] = s + fb;
  }
  __syncthreads();
  float val = (tid < 196) ? es[tid] : -3.0e38f;
  red[tid] = val; __syncthreads();
  for (int s=128; s>0; s>>=1){ if (tid<s) red[tid] = fmaxf(red[tid], red[tid+s]); __syncthreads(); }
  float m = red[0]; __syncthreads();
  float ex = (tid<196)? expf(val - m) : 0.f;
  red[tid] = ex; __syncthreads();
  for (int s=128; s>0; s>>=1){ if (tid<s) red[tid] += red[tid+s]; __syncthreads(); }
  float inv = 1.f / red[0];
  __syncthreads();
  if (tid < 196) es[tid] = ex * inv;
  if (q == 0 && tid < 196){
    int active = t < clen[b]-1;
    out[OUT_ALPH + ((size_t)b*29 + t)*196 + tid] = active ? ex*inv : 0.f;
  }
  __syncthreads();
  int d = q*512 + tid*2;
  const unsigned short* ep = ench + (size_t)b*196*2048 + d;
  float acc0 = 0.f, acc1 = 0.f;
  for (int p=0;p<196;p++){
    unsigned v = *(const unsigned*)(ep + (size_t)p*2048);
    float al = es[p];
    acc0 += al * bf2f((unsigned short)(v & 0xffffu));
    acc1 += al * bf2f((unsigned short)(v >> 16));
  }
  float g0 = gate[b*2048 + d], g1 = gate[b*2048 + d + 1];
  xhi[(size_t)b*3072 + 512 + d]     = f2bf(acc0 * g0);
  xhi[(size_t)b*3072 + 512 + d + 1] = f2bf(acc1 * g1);
}

// ---------------- gates GEMM: x_hi @ [wih;whh] dual-B, K-split 4 ----------------
__global__ __launch_bounds__(256) void g_gates(const unsigned short* __restrict__ X,
    const unsigned short* __restrict__ BH, const unsigned short* __restrict__ BL,
    float* __restrict__ part){
  int nb = blockIdx.x, kc = blockIdx.y;              // 32 x 4
  int tid = threadIdx.x, w = tid >> 6, l = tid & 63;
  int r = l & 15, g = l >> 4;
  int n0 = nb*64, nt0 = n0 >> 4;
  const unsigned short* a0 = X + (size_t)(w*16 + r)*3072 + g*8;
  v4f acc[4];
  #pragma unroll
  for (int j=0;j<4;j++) acc[j] = 0.f;
  for (int k2=0; k2<24; ++k2){
    int kt = kc*24 + k2;
    v8s a = *(const v8s*)(a0 + kt*32);
    #pragma unroll
    for (int nj=0;nj<4;nj++){
      size_t bi = (((size_t)(nt0+nj)*96 + kt)*64 + l)*8;
      v8s bh = *(const v8s*)(BH + bi);
      v8s bl = *(const v8s*)(BL + bi);
      acc[nj] = __builtin_amdgcn_mfma_f32_16x16x32_bf16(a, bh, acc[nj],0,0,0);
      acc[nj] = __builtin_amdgcn_mfma_f32_16x16x32_bf16(a, bl, acc[nj],0,0,0);
    }
  }
  float* pp = part + (size_t)kc*131072;
  #pragma unroll
  for (int nj=0;nj<4;nj++){
    int col = n0 + nj*16 + r;
    #pragma unroll
    for (int rr=0;rr<4;rr++){
      int b_ = w*16 + g*4 + rr;
      pp[b_*2048 + col] = acc[nj][rr];
    }
  }
}

// ---------------- LSTM elementwise + hh_bf + state update + emb prefetch ----------------
__global__ void k_s2b(const float* __restrict__ part, const float* __restrict__ bih,
    const float* __restrict__ bhh, const int* __restrict__ clen,
    const int* __restrict__ caps, const float* __restrict__ embd,
    float* __restrict__ h, float* __restrict__ c, unsigned short* __restrict__ xhi,
    unsigned short* __restrict__ hhb, int t){
  int idx = blockIdx.x*256 + threadIdx.x;            // 32768
  int b = idx >> 9, d = idx & 511;
  float gi = bih[d]      + bhh[d];
  float gf = bih[512+d]  + bhh[512+d];
  float gg = bih[1024+d] + bhh[1024+d];
  float go = bih[1536+d] + bhh[1536+d];
  #pragma unroll
  for (int kc=0;kc<4;kc++){
    const float* p = part + (size_t)kc*131072 + b*2048;
    gi += p[d]; gf += p[512+d]; gg += p[1024+d]; go += p[1536+d];
  }
  float cn = sigm(gf)*c[idx] + sigm(gi)*tanhf(gg);
  float hn = sigm(go)*tanhf(cn);
  hhb[(size_t)(t*64+b)*512 + d] = f2bf(hn);
  if (t < clen[b]-1){
    h[idx] = hn; c[idx] = cn;
    xhi[(size_t)b*3072 + 2560 + d] = f2bf(hn);
  }
  xhi[(size_t)b*3072 + d] = f2bf(embd[(size_t)caps[b*30 + t + 1]*512 + d]);
}

// ---------------- batched preds MFMA: hh_bf @ fcw + fcb, masked ----------------
__global__ __launch_bounds__(256) void g_preds(const unsigned short* __restrict__ A,
    const unsigned short* __restrict__ B, const float* __restrict__ bias,
    const int* __restrict__ clen, float* __restrict__ out){
  int log = ((blockIdx.x & 7) * 145) + (blockIdx.x >> 3);  // 1160 blocks
  int mb = log % 29, nb = log / 29;
  int tid = threadIdx.x, w = tid >> 6, l = tid & 63;
  int r = l & 15, g = l >> 4;
  int m0 = mb * 64;
  int n0 = nb * 256 + w * 64;
  int nt0 = n0 >> 4;
  const unsigned short* a0 = A + (size_t)(m0 + r)*512 + g*8;
  v4f acc[4][4];
  #pragma unroll
  for (int i=0;i<4;i++){ acc[i][0]=0.f; acc[i][1]=0.f; acc[i][2]=0.f; acc[i][3]=0.f; }
  for (int kt=0; kt<16; ++kt){
    v8s a[4];
    #pragma unroll
    for (int mi=0;mi<4;mi++)
      a[mi] = *(const v8s*)(a0 + (size_t)mi*16*512 + kt*32);
    #pragma unroll
    for (int nj=0;nj<4;nj++){
      v8s b = *(const v8s*)(B + (((size_t)(nt0+nj)*16 + kt)*64 + l)*8);
      #pragma unroll
      for (int mi=0;mi<4;mi++)
        acc[mi][nj] = __builtin_amdgcn_mfma_f32_16x16x32_bf16(a[mi], b, acc[mi][nj],0,0,0);
    }
  }
  int t = mb;
  #pragma unroll
  for (int nj=0;nj<4;nj++){
    int col = n0 + nj*16 + r;
    if (col < 10000){
      float bv = bias[col];
      #pragma unroll
      for (int mi=0;mi<4;mi++){
        #pragma unroll
        for (int rr=0;rr<4;rr++){
          int b_ = mi*16 + g*4 + rr;
          int active = t < clen[b_]-1;
          out[OUT_PRED + ((size_t)b_*29 + t)*10000 + col] = active ? acc[mi][nj][rr] + bv : 0.f;
        }
      }
    }
  }
}

// ---------------- passthrough outputs + x emb init for t=0 ----------------
__global__ void k_misc(const int* __restrict__ caps, const int* __restrict__ clen,
                       float* __restrict__ out){
  int tid = threadIdx.x;
  for (int i=tid;i<64*30;i+=256) out[OUT_CAPS+i] = (float)caps[i];
  if (tid<64) out[OUT_DLEN+tid] = (float)(clen[tid]-1);
}
__global__ void k_emb0(const int* __restrict__ caps, const float* __restrict__ embd,
                       unsigned short* __restrict__ xhi){
  int idx = blockIdx.x*256 + threadIdx.x;            // 32768
  int b = idx >> 9, d = idx & 511;
  xhi[(size_t)b*3072 + d] = f2bf(embd[(size_t)caps[b*30]*512 + d]);
}

extern "C" void kernel_launch(void* const* d_in, const int* in_sizes, int n_in,
                              void* d_out, int out_size, void* d_ws, size_t ws_size,
                              hipStream_t stream){
  (void)in_sizes; (void)n_in; (void)out_size; (void)ws_size;
  const float* enc = (const float*)d_in[0];
  const int*   caps= (const int*)d_in[1];
  const int*   clen= (const int*)d_in[2];
  const float* embd= (const float*)d_in[3];
  const float* eaw = (const float*)d_in[4];
  const float* eab = (const float*)d_in[5];
  const float* daw = (const float*)d_in[6];
  const float* dab = (const float*)d_in[7];
  const float* faw = (const float*)d_in[8];
  const float* fab = (const float*)d_in[9];
  const float* ihw = (const float*)d_in[10];
  const float* ihb = (const float*)d_in[11];
  const float* icw = (const float*)d_in[12];
  const float* icb = (const float*)d_in[13];
  const float* fbw = (const float*)d_in[14];
  const float* fbb = (const float*)d_in[15];
  const float* wih = (const float*)d_in[16];
  const float* whh = (const float*)d_in[17];
  const float* bih = (const float*)d_in[18];
  const float* bhh = (const float*)d_in[19];
  const float* fcw = (const float*)d_in[20];
  const float* fcb = (const float*)d_in[21];

  char* W = (char*)d_ws;
  unsigned short* ench = (unsigned short*)(W + O_ENCH);
  float*          att1 = (float*)(W + O_ATT1);
  unsigned short* peh  = (unsigned short*)(W + O_PEH);
  unsigned short* pel  = (unsigned short*)(W + O_PEL);
  unsigned short* psm  = (unsigned short*)(W + O_PSM);
  unsigned short* pgh  = (unsigned short*)(W + O_PGH);
  unsigned short* pgl  = (unsigned short*)(W + O_PGL);
  unsigned short* pfc  = (unsigned short*)(W + O_PFC);
  unsigned short* pin  = (unsigned short*)(W + O_PIN);
  float*          mean = (float*)(W + O_MEAN);
  unsigned short* meanb= (unsigned short*)(W + O_MEANB);
  float*          h    = (float*)(W + O_H);
  float*          c    = (float*)(W + O_C);
  float*          at2  = (float*)(W + O_AT2);
  float*          gate = (float*)(W + O_GATE);
  unsigned short* xhi  = (unsigned short*)(W + O_XHI);
  float*          part = (float*)(W + O_PART);
  unsigned short* hhb  = (unsigned short*)(W + O_HHB);
  float* out = (float*)d_out;

  k_cvt_enc<<<12544,256,0,stream>>>(enc, ench);
  k_mean<<<dim3(8,64),256,0,stream>>>(enc, mean, meanb);
  pack_eaw  <<<512, 256,0,stream>>>(eaw, peh, pel);
  pack_small<<<640, 256,0,stream>>>(daw, fbw, psm);
  pack_gates<<<3072,256,0,stream>>>(wih, whh, pgh, pgl);
  pack_fc   <<<2560,256,0,stream>>>(fcw, pfc);
  pack_init <<<1024,256,0,stream>>>(ihw, icw, pin);
  g_init<<<16,256,0,stream>>>(meanb, pin, ihb, icb, h, c, xhi);
  k_emb0<<<128,256,0,stream>>>(caps, embd, xhi);
  k_misc<<<1,256,0,stream>>>(caps, clen, out);
  g_att1<<<392,256,0,stream>>>(ench, peh, pel, eab, att1);

  for (int t=0;t<29;t++){
    g_small<<<40,256,0,stream>>>(xhi, psm, dab, fbb, at2, gate);
    k_attn<<<256,256,0,stream>>>(att1, at2, faw, fab, ench, gate, clen, xhi, out, t);
    g_gates<<<dim3(32,4),256,0,stream>>>(xhi, pgh, pgl, part);
    k_s2b<<<128,256,0,stream>>>(part, bih, bhh, clen, caps, embd, h, c, xhi, hhb, t);
  }

  g_preds<<<1160,256,0,stream>>>(hhb, pfc, fcb, clen, out);
}